// Round 4
// baseline (9846.238 us; speedup 1.0000x reference)
//
#include <hip/hip_runtime.h>

typedef unsigned short u16;
typedef unsigned int   u32;
typedef __attribute__((ext_vector_type(4))) u16   u16x4;
typedef __attribute__((ext_vector_type(8))) u16   u16x8;
typedef __attribute__((ext_vector_type(8))) __bf16 bf16x8;
typedef __attribute__((ext_vector_type(4))) float  floatx4;
typedef __attribute__((ext_vector_type(4))) u32   u32x4;

#define TT 512   // seq len
#define BB 64    // batch
#define HD 512   // hidden/emb dim
#define SENT 0xAAAAAAAAu

// ---------- helpers ----------
__device__ __forceinline__ u16 f2bf(float f) {
  u32 u = __builtin_bit_cast(u32, f);
  u32 r = u + 0x7fffu + ((u >> 16) & 1u);   // round-to-nearest-even
  return (u16)(r >> 16);
}
__device__ __forceinline__ float bf2f(u16 h) {
  return __builtin_bit_cast(float, ((u32)h) << 16);
}
__device__ __forceinline__ float fast_tanh(float x) {
  float xc = fminf(fmaxf(x, -12.f), 12.f);
  float e = __expf(2.f * xc);
  return __fdividef(e - 1.f, e + 1.f);
}

// Coherent write-through store: *(base + OFF bytes) <- val  (value ready before issue)
#define GST(val, base, OFF) \
  asm volatile("global_store_dword %0, %1, off offset:" OFF " sc0 sc1" \
               :: "v"(base), "v"(val) : "memory")

// ---------- prep: convert weights to bf16, sum biases ----------
__global__ __launch_bounds__(256)
void prep_kernel(const float* __restrict__ W_ih, const float* __restrict__ W_hh,
                 const float* __restrict__ b_ih, const float* __restrict__ b_hh,
                 u16* __restrict__ wbf, float* __restrict__ bsum) {
  int idx = blockIdx.x * blockDim.x + threadIdx.x;
  int stride = gridDim.x * blockDim.x;
  for (int i = idx; i < 4 * 262144; i += stride) {
    int mat = i >> 18;
    int off = i & 262143;
    const float* src = (mat == 0) ? W_ih : (mat == 1) ? W_hh
                     : (mat == 2) ? (W_ih + 262144) : (W_hh + 262144);
    wbf[i] = f2bf(src[off]);
  }
  if (idx < 1024) bsum[idx] = b_ih[idx] + b_hh[idx];
}

// ---------- pre-activation GEMM ----------
// Xpre[m][n] = A[m][:] @ W[n][:] + bsum[n],  M=T*B (m = t*64+b), K=512, N=512
// mode 0: A row = emb[x[b][t]] (fp32 -> bf16)
// mode 1: A row = hi-bf16 stream of hist slot t+1 (SoA layout: row = [hi x512 | lo x512])
__global__ __launch_bounds__(256, 2)
void gemm_pre(const u16* __restrict__ Bw, const float* __restrict__ bsum,
              const float* __restrict__ embsrc, const int* __restrict__ xtok,
              const u32* __restrict__ hist, float* __restrict__ Xpre, int mode) {
  __shared__ u16 As[128][40];
  __shared__ u16 Bs[128][40];
  const int tid = threadIdx.x;
  const int wave = tid >> 6, lane = tid & 63;
  const int quad = lane >> 4, l16 = lane & 15;
  const int mtile = blockIdx.x >> 2, ntile = blockIdx.x & 3;
  const int m0 = mtile * 128, n0 = ntile * 128;
  const int srow = tid >> 1, half = tid & 1;

  const float* aF = nullptr; const u32* aU = nullptr;
  {
    const int grow = m0 + srow;
    if (mode == 0) {
      const int t = grow >> 6, b = grow & 63;
      const int tok = xtok[b * TT + t];
      aF = embsrc + (size_t)tok * 512 + half * 16;
    } else {
      // hi region of row: u32s [0..255]; this thread covers u32s half*8 + ks*16 + {0..7}
      aU = hist + (size_t)((grow >> 6) + 1) * 32768 + (size_t)(grow & 63) * 512 + half * 8;
    }
  }
  const u16* bptr = Bw + (size_t)(n0 + srow) * 512 + half * 16;

  floatx4 acc[2][8];
#pragma unroll
  for (int a = 0; a < 2; a++)
#pragma unroll
    for (int b = 0; b < 8; b++) acc[a][b] = (floatx4){0.f, 0.f, 0.f, 0.f};

  for (int ks = 0; ks < 16; ks++) {
    const int k0 = ks * 32;
    u32 packed[8];
    if (mode == 0) {
      const float4* p = (const float4*)(aF + k0);
      float4 f0 = p[0], f1 = p[1], f2 = p[2], f3 = p[3];
      float vals[16] = {f0.x, f0.y, f0.z, f0.w, f1.x, f1.y, f1.z, f1.w,
                        f2.x, f2.y, f2.z, f2.w, f3.x, f3.y, f3.z, f3.w};
#pragma unroll
      for (int j = 0; j < 8; j++)
        packed[j] = (u32)f2bf(vals[2 * j]) | ((u32)f2bf(vals[2 * j + 1]) << 16);
    } else {
      const u32x4* p = (const u32x4*)(aU + (size_t)ks * 16);
      u32x4 q0 = p[0], q1 = p[1];
      packed[0] = q0[0]; packed[1] = q0[1]; packed[2] = q0[2]; packed[3] = q0[3];
      packed[4] = q1[0]; packed[5] = q1[1]; packed[6] = q1[2]; packed[7] = q1[3];
    }
    {
      u32x4* adst = (u32x4*)&As[srow][half * 16];
      adst[0] = (u32x4){packed[0], packed[1], packed[2], packed[3]};
      adst[1] = (u32x4){packed[4], packed[5], packed[6], packed[7]};
    }
    {
      const u32x4* bp = (const u32x4*)(bptr + k0);
      u32x4 b0 = bp[0], b1 = bp[1];
      u32x4* bdst = (u32x4*)&Bs[srow][half * 16];
      bdst[0] = b0; bdst[1] = b1;
    }
    __syncthreads();
    bf16x8 afr[2], bfr[8];
#pragma unroll
    for (int mt = 0; mt < 2; mt++)
      afr[mt] = __builtin_bit_cast(bf16x8, *(const u16x8*)&As[wave * 32 + mt * 16 + l16][quad * 8]);
#pragma unroll
    for (int nt = 0; nt < 8; nt++)
      bfr[nt] = __builtin_bit_cast(bf16x8, *(const u16x8*)&Bs[nt * 16 + l16][quad * 8]);
#pragma unroll
    for (int mt = 0; mt < 2; mt++)
#pragma unroll
      for (int nt = 0; nt < 8; nt++)
        acc[mt][nt] = __builtin_amdgcn_mfma_f32_16x16x32_bf16(afr[mt], bfr[nt], acc[mt][nt], 0, 0, 0);
    __syncthreads();
  }
  float bs[8];
#pragma unroll
  for (int nt = 0; nt < 8; nt++) bs[nt] = bsum[n0 + nt * 16 + l16];
#pragma unroll
  for (int mt = 0; mt < 2; mt++)
#pragma unroll
    for (int nt = 0; nt < 8; nt++)
#pragma unroll
      for (int i = 0; i < 4; i++) {
        const int gm = m0 + wave * 32 + mt * 16 + quad * 4 + i;
        Xpre[(size_t)gm * 512 + n0 + nt * 16 + l16] = acc[mt][nt][i] + bs[nt];
      }
}

// ---------- sequential recurrence pass (one layer) ----------
// 32 wgs: c = blockIdx>>2 (column slice of 64), g = blockIdx&3 (batch tile of 16).
// hist slot s row layout (SoA, 2048 B): [hi bf16 x512 | lo bf16 x512] of h(s-1).
// Self-validating u32 words (sentinel 0xAAAAAAAA), exchanged with pipelined
// cache-bypassing loads. ALL 32 loads + waitcnt live in ONE asm block so the
// outputs are born valid (round-3 bug: split blocks let the compiler touch
// in-flight registers). Non-duplicated weights: wfrag[16] reused for hi & lo.
__global__ __launch_bounds__(256, 1)
void rnn_pass(const u16* __restrict__ Whh, const float* __restrict__ Xpre,
              u32* __restrict__ hist, const int* __restrict__ lengths,
              float* __restrict__ out_last, float* __restrict__ out_hidden) {
  const int tid = threadIdx.x;
  const int wave = tid >> 6, lane = tid & 63;
  const int quad = lane >> 4, l16 = lane & 15;
  const int c = blockIdx.x >> 2, g = blockIdx.x & 3;
  const int mycol = c * 64 + wave * 16 + l16;

  // Non-duplicated B-fragments: wfrag[j] = W[mycol][j*32 + quad*8 .. +7]  (64 VGPRs)
  bf16x8 wfrag[16];
  {
    const u16* wrow = Whh + (size_t)mycol * 512 + quad * 8;
#pragma unroll
    for (int j = 0; j < 16; j++)
      wfrag[j] = __builtin_bit_cast(bf16x8, *(const u16x8*)(wrow + j * 32));
  }
  float hcur[4];
  int lens[4];
  const int myrow0 = g * 16 + quad * 4;
#pragma unroll
  for (int i = 0; i < 4; i++) {
    hcur[i] = 0.f;
    lens[i] = lengths[myrow0 + i];
  }
  float pre[4];
#pragma unroll
  for (int i = 0; i < 4; i++)
    pre[i] = Xpre[(size_t)(myrow0 + i) * 512 + mycol];

  for (int t = 0; t < TT; t++) {
    // ---- poll h(t-1): lane reads its own A-fragments (row g*16+l16, quad's columns)
    // byte offsets s*64 cover hi region (s=0..15) then lo region (s=16..31)
    const u32* ab = hist + (size_t)t * 32768 + (size_t)(g * 16 + l16) * 512 + quad * 4;
    u32x4 v[32];
    int guard = 0;
    while (true) {
      asm volatile(
        "global_load_dwordx4 %0,  %32, off sc0 sc1\n\t"
        "global_load_dwordx4 %1,  %32, off offset:64 sc0 sc1\n\t"
        "global_load_dwordx4 %2,  %32, off offset:128 sc0 sc1\n\t"
        "global_load_dwordx4 %3,  %32, off offset:192 sc0 sc1\n\t"
        "global_load_dwordx4 %4,  %32, off offset:256 sc0 sc1\n\t"
        "global_load_dwordx4 %5,  %32, off offset:320 sc0 sc1\n\t"
        "global_load_dwordx4 %6,  %32, off offset:384 sc0 sc1\n\t"
        "global_load_dwordx4 %7,  %32, off offset:448 sc0 sc1\n\t"
        "global_load_dwordx4 %8,  %32, off offset:512 sc0 sc1\n\t"
        "global_load_dwordx4 %9,  %32, off offset:576 sc0 sc1\n\t"
        "global_load_dwordx4 %10, %32, off offset:640 sc0 sc1\n\t"
        "global_load_dwordx4 %11, %32, off offset:704 sc0 sc1\n\t"
        "global_load_dwordx4 %12, %32, off offset:768 sc0 sc1\n\t"
        "global_load_dwordx4 %13, %32, off offset:832 sc0 sc1\n\t"
        "global_load_dwordx4 %14, %32, off offset:896 sc0 sc1\n\t"
        "global_load_dwordx4 %15, %32, off offset:960 sc0 sc1\n\t"
        "global_load_dwordx4 %16, %32, off offset:1024 sc0 sc1\n\t"
        "global_load_dwordx4 %17, %32, off offset:1088 sc0 sc1\n\t"
        "global_load_dwordx4 %18, %32, off offset:1152 sc0 sc1\n\t"
        "global_load_dwordx4 %19, %32, off offset:1216 sc0 sc1\n\t"
        "global_load_dwordx4 %20, %32, off offset:1280 sc0 sc1\n\t"
        "global_load_dwordx4 %21, %32, off offset:1344 sc0 sc1\n\t"
        "global_load_dwordx4 %22, %32, off offset:1408 sc0 sc1\n\t"
        "global_load_dwordx4 %23, %32, off offset:1472 sc0 sc1\n\t"
        "global_load_dwordx4 %24, %32, off offset:1536 sc0 sc1\n\t"
        "global_load_dwordx4 %25, %32, off offset:1600 sc0 sc1\n\t"
        "global_load_dwordx4 %26, %32, off offset:1664 sc0 sc1\n\t"
        "global_load_dwordx4 %27, %32, off offset:1728 sc0 sc1\n\t"
        "global_load_dwordx4 %28, %32, off offset:1792 sc0 sc1\n\t"
        "global_load_dwordx4 %29, %32, off offset:1856 sc0 sc1\n\t"
        "global_load_dwordx4 %30, %32, off offset:1920 sc0 sc1\n\t"
        "global_load_dwordx4 %31, %32, off offset:1984 sc0 sc1\n\t"
        "s_waitcnt vmcnt(0)"
        : "=v"(v[0]),  "=v"(v[1]),  "=v"(v[2]),  "=v"(v[3]),
          "=v"(v[4]),  "=v"(v[5]),  "=v"(v[6]),  "=v"(v[7]),
          "=v"(v[8]),  "=v"(v[9]),  "=v"(v[10]), "=v"(v[11]),
          "=v"(v[12]), "=v"(v[13]), "=v"(v[14]), "=v"(v[15]),
          "=v"(v[16]), "=v"(v[17]), "=v"(v[18]), "=v"(v[19]),
          "=v"(v[20]), "=v"(v[21]), "=v"(v[22]), "=v"(v[23]),
          "=v"(v[24]), "=v"(v[25]), "=v"(v[26]), "=v"(v[27]),
          "=v"(v[28]), "=v"(v[29]), "=v"(v[30]), "=v"(v[31])
        : "v"(ab)
        : "memory");
      u32 m = 0xFFFFFFFFu;   // min over (word ^ SENT); 0 iff any word still sentinel
#pragma unroll
      for (int j = 0; j < 32; j++) {
        u32 a0 = v[j][0] ^ SENT, a1 = v[j][1] ^ SENT;
        u32 a2 = v[j][2] ^ SENT, a3 = v[j][3] ^ SENT;
        u32 mm = a0 < a1 ? a0 : a1;
        u32 nn = a2 < a3 ? a2 : a3;
        mm = mm < nn ? mm : nn;
        m = mm < m ? mm : m;
      }
      if (!__any(m == 0)) break;
      if (++guard > (1 << 17)) break;      // terminate rather than hang
      __builtin_amdgcn_s_sleep(1);
    }

    // ---- prefetch Xpre for t+1 (a full poll+MFMA of latency to land)
    float pnx[4];
    {
      const int tp = (t + 1 < TT) ? t + 1 : TT - 1;
#pragma unroll
      for (int i = 0; i < 4; i++)
        pnx[i] = Xpre[(size_t)tp * 32768 + (size_t)(myrow0 + i) * 512 + mycol];
    }

    // ---- MFMA: s=0..15 hi-part contributions, s=16..31 lo-part; same weights
    floatx4 ac[4];
#pragma unroll
    for (int q = 0; q < 4; q++) ac[q] = (floatx4){0.f, 0.f, 0.f, 0.f};
#pragma unroll
    for (int s = 0; s < 32; s++) {
      bf16x8 a = __builtin_bit_cast(bf16x8, v[s]);
      ac[s & 3] = __builtin_amdgcn_mfma_f32_16x16x32_bf16(a, wfrag[s & 15], ac[s & 3], 0, 0, 0);
    }

    // ---- epilogue: tanh + mask; pack adjacent-lane pair into u32 words; publish
    u32 hiw[4], low[4];
#pragma unroll
    for (int i = 0; i < 4; i++) {
      const float vsum = ac[0][i] + ac[1][i] + ac[2][i] + ac[3][i] + pre[i];
      const float th = fast_tanh(vsum);
      const float nv = (t < lens[i]) ? th : hcur[i];
      hcur[i] = nv;
      const u16 hi = f2bf(nv);
      const u16 lo = f2bf(nv - bf2f(hi));
      u32 pk = (u32)hi | ((u32)lo << 16);
      u32 other = __shfl_xor((int)pk, 1, 64);   // partner col mycol^1 (both lanes active)
      u32 hw = (pk & 0xffffu) | (other << 16);          // hi_even | hi_odd<<16
      u32 lw = (pk >> 16) | (other & 0xffff0000u);      // lo_even | lo_odd<<16
      hw += (hw == SENT);   // exclude sentinel (1 ulp of a ~1e-13 bf16 — harmless)
      lw += (lw == SENT);
      hiw[i] = hw; low[i] = lw;
    }
    if (!(l16 & 1)) {   // even lanes own the packed words
      char* rb  = (char*)hist + (size_t)(t + 1) * 131072 + (size_t)myrow0 * 2048 + (size_t)mycol * 2;
      char* rb2 = rb + 4096;
      GST(hiw[0], rb,  "0");    GST(low[0], rb,  "1024");
      GST(hiw[1], rb,  "2048"); GST(low[1], rb,  "3072");
      GST(hiw[2], rb2, "0");    GST(low[2], rb2, "1024");
      GST(hiw[3], rb2, "2048"); GST(low[3], rb2, "3072");
    }
#pragma unroll
    for (int i = 0; i < 4; i++) pre[i] = pnx[i];
  }
  // final hidden state (fp32 registers, post-mask)
#pragma unroll
  for (int i = 0; i < 4; i++) {
    const int b = myrow0 + i;
    if (out_hidden) out_hidden[(size_t)b * 1024 + mycol] = hcur[i];
    if (out_last)   out_last[(size_t)b * 512 + mycol] = hcur[i];
  }
}

// ---------- launch ----------
extern "C" void kernel_launch(void* const* d_in, const int* in_sizes, int n_in,
                              void* d_out, int out_size, void* d_ws, size_t ws_size,
                              hipStream_t stream) {
  const int*   x   = (const int*)d_in[0];
  const int*   len = (const int*)d_in[1];
  const float* emb = (const float*)d_in[2];
  const float* Wih = (const float*)d_in[3];
  const float* Whh = (const float*)d_in[4];
  const float* bih = (const float*)d_in[5];
  const float* bhh = (const float*)d_in[6];
  float* out = (float*)d_out;

  char* ws = (char*)d_ws;
  float* Xpre  = (float*)(ws);                   // 67,108,864 B (T*B*512 fp32), reused for both layers
  u32*   hist  = (u32*)(ws + 67108864);          // 67,239,936 B ((T+1)*B*512 u32), reused for both layers
  u16*   wbf   = (u16*)(ws + 134348800);         // 2,097,152 B
  float* bsum  = (float*)(ws + 136445952);       // 4,096 B

  // slot 0 = h(-1) = 0 (valid zeros); slots 1..512 = sentinel poison
  hipMemsetAsync(hist, 0, 131072, stream);
  hipMemsetAsync((char*)hist + 131072, 0xAA, (size_t)512 * 131072, stream);
  hipLaunchKernelGGL(prep_kernel, dim3(512), dim3(256), 0, stream, Wih, Whh, bih, bhh, wbf, bsum);
  // layer 0 pre: emb gather GEMM
  hipLaunchKernelGGL(gemm_pre, dim3(1024), dim3(256), 0, stream,
                     wbf /*wih0*/, bsum, emb, x, (const u32*)nullptr, Xpre, 0);
  // layer 0 recurrence
  hipLaunchKernelGGL(rnn_pass, dim3(32), dim3(256), 0, stream,
                     wbf + 262144 /*whh0*/, Xpre, hist, len,
                     (float*)nullptr, out + 32768 /*hidden[:,0,:]*/);
  // layer 1 pre: h0 history GEMM (reads hi streams of hist slots 1..512)
  hipLaunchKernelGGL(gemm_pre, dim3(1024), dim3(256), 0, stream,
                     wbf + 524288 /*wih1*/, bsum + 512, (const float*)nullptr, (const int*)nullptr,
                     hist, Xpre, 1);
  // re-poison hist slots 1..512 for pass 2
  hipMemsetAsync((char*)hist + 131072, 0xAA, (size_t)512 * 131072, stream);
  // layer 1 recurrence
  hipLaunchKernelGGL(rnn_pass, dim3(32), dim3(256), 0, stream,
                     wbf + 786432 /*whh1*/, Xpre, hist, len,
                     out /*h_last*/, out + 32768 + 512 /*hidden[:,1,:]*/);
}